// Round 1
// baseline (1790.284 us; speedup 1.0000x reference)
//
#include <hip/hip_runtime.h>
#include <hip/hip_fp16.h>

// Problem constants
// tensor  [B=512, T=64, N=512] f32
// W_shared[R=64, N=512, R=64]  f32
// W_last  [C=100, R=64, M=64, R=64] f32
// out     [C=100, B=512] f32
//
// Algebra: state collapses to v_b (len 64): v_b <- v_b @ M_b(t),
//   M_b(t)[i,k] = sum_j x[b,t,j] * W_shared[i,j,k]
// out[c,b] = sum_i v_b[i] * u[c,i],  u[c,i] = sum_{m,k} W_last[c,i,m,k]

#define BM 128
#define BN 64
#define BK 32

// ---------------- K1: u[c,i] = sum over 4096 contiguous floats ----------------
__global__ __launch_bounds__(256) void k_usum(const float* __restrict__ Wl,
                                              float* __restrict__ u) {
    int ci = blockIdx.x;  // 0..6399  (c*64 + i)
    const float4* p = (const float4*)(Wl + (size_t)ci * 4096);
    int tid = threadIdx.x;
    float s = 0.f;
#pragma unroll
    for (int q = 0; q < 4; ++q) {
        float4 v = p[tid + 256 * q];
        s += v.x + v.y + v.z + v.w;
    }
    __shared__ float red[256];
    red[tid] = s;
    __syncthreads();
    if (tid < 128) red[tid] += red[tid + 128];
    __syncthreads();
    if (tid < 64) {
        float x = red[tid] + red[tid + 64];
#pragma unroll
        for (int off = 32; off > 0; off >>= 1) x += __shfl_down(x, off, 64);
        if (tid == 0) u[ci] = x;
    }
}

// ---------------- K2: GEMM  bik[m, i*64+k] = sum_j A[m,j] * W[i,j,k] ----------
// A row m is at A + a_off + m*a_stride (so the same kernel serves the big path
// with m=(b*64+t), a_stride=512 and the per-t path with m=b, a_stride=32768).
// Block: (blockIdx.x = i0 in 0..63, blockIdx.y = row block of 128).
// W tile for (i0, j-range) is a fully contiguous float chunk.
__global__ __launch_bounds__(256) void k_gemm(const float* __restrict__ A,
                                              const float* __restrict__ W,
                                              __half* __restrict__ out,
                                              int a_off, int a_stride) {
    __shared__ float As[BK * BM];  // As[kk*BM + row]
    __shared__ float Bs[BK * BN];  // Bs[kk*BN + k]
    int i0 = blockIdx.x;
    int m0 = blockIdx.y * BM;
    int tid = threadIdx.x;
    int tx = tid & 15, ty = tid >> 4;
    float acc[8][4];
#pragma unroll
    for (int q = 0; q < 8; ++q)
#pragma unroll
        for (int c = 0; c < 4; ++c) acc[q][c] = 0.f;

    const float* wbase = W + (size_t)i0 * 32768;

    for (int j0 = 0; j0 < 512; j0 += BK) {
        // A tile: 128 rows x 32 cols, stored transposed As[kk][row]
        {
            int c4 = tid & 7;   // which float4 within the 32-float row chunk
            int r = tid >> 3;   // 0..31
#pragma unroll
            for (int p = 0; p < 4; ++p) {
                int row = r + 32 * p;
                float4 v = *(const float4*)(A + (size_t)a_off +
                                            (size_t)(m0 + row) * a_stride + j0 + 4 * c4);
                As[(4 * c4 + 0) * BM + row] = v.x;
                As[(4 * c4 + 1) * BM + row] = v.y;
                As[(4 * c4 + 2) * BM + row] = v.z;
                As[(4 * c4 + 3) * BM + row] = v.w;
            }
            // B tile: contiguous 2048 floats starting at wbase + j0*64
            const float4* src = (const float4*)(wbase + (size_t)j0 * 64);
            float4* dst = (float4*)Bs;
            dst[tid] = src[tid];
            dst[tid + 256] = src[tid + 256];
        }
        __syncthreads();
#pragma unroll
        for (int kk = 0; kk < BK; ++kk) {
            float bv[4], av[8];
#pragma unroll
            for (int c = 0; c < 4; ++c) bv[c] = Bs[kk * BN + 4 * tx + c];
#pragma unroll
            for (int q = 0; q < 8; ++q) av[q] = As[kk * BM + 8 * ty + q];
#pragma unroll
            for (int q = 0; q < 8; ++q)
#pragma unroll
                for (int c = 0; c < 4; ++c) acc[q][c] += av[q] * bv[c];
        }
        __syncthreads();
    }
    // store fp16
#pragma unroll
    for (int q = 0; q < 8; ++q) {
        int m = m0 + 8 * ty + q;
        __half* o = out + (size_t)m * 4096 + i0 * 64 + 4 * tx;
#pragma unroll
        for (int c = 0; c < 4; ++c) o[c] = __float2half(acc[q][c]);
    }
}

// ---------------- K3 (big path): per-b sequential scan over 64 steps ----------
__global__ __launch_bounds__(256) void k_scan(const __half* __restrict__ bik,
                                              float* __restrict__ v_all) {
    int b = blockIdx.x;
    int tid = threadIdx.x;
    int k = tid & 63, grp = tid >> 6;
    __shared__ float vsh[64];
    __shared__ float part[256];
    if (tid < 64) vsh[tid] = 1.0f;
    __syncthreads();
    const __half* base = bik + (size_t)b * 64 * 4096;
    for (int t = 0; t < 64; ++t) {
        const __half* Mt = base + (size_t)t * 4096;
        float s = 0.f;
#pragma unroll
        for (int q = 0; q < 16; ++q) {
            int i = grp * 16 + q;
            s += vsh[i] * __half2float(Mt[i * 64 + k]);
        }
        part[tid] = s;
        __syncthreads();
        if (tid < 64) vsh[k] = part[k] + part[64 + k] + part[128 + k] + part[192 + k];
        __syncthreads();
    }
    if (tid < 64) v_all[(size_t)b * 64 + tid] = vsh[tid];
}

// ---------------- K3' (fallback path): one recurrence step for all b ----------
__global__ __launch_bounds__(256) void k_update(const __half* __restrict__ Mt,
                                                const float* __restrict__ vin,
                                                float* __restrict__ vout, int first) {
    int o = blockIdx.x * 256 + threadIdx.x;  // 0..32767  (b*64 + k)
    int b = o >> 6, k = o & 63;
    const __half* m = Mt + (size_t)b * 4096;
    float s = 0.f;
    if (first) {
#pragma unroll 8
        for (int i = 0; i < 64; ++i) s += __half2float(m[i * 64 + k]);
    } else {
        const float* v = vin + (size_t)b * 64;
#pragma unroll 8
        for (int i = 0; i < 64; ++i) s += v[i] * __half2float(m[i * 64 + k]);
    }
    vout[o] = s;
}

// ---------------- K4: out[c,b] = sum_i u[c,i] * v[b,i] ------------------------
__global__ __launch_bounds__(256) void k_final(const float* __restrict__ u,
                                               const float* __restrict__ v,
                                               float* __restrict__ out) {
    int o = blockIdx.x * 256 + threadIdx.x;  // 0..51199  (c*512 + b)
    int c = o >> 9, b = o & 511;
    const float* uc = u + c * 64;
    const float* vb = v + (size_t)b * 64;
    float s = 0.f;
#pragma unroll 8
    for (int i = 0; i < 64; ++i) s += uc[i] * vb[i];
    out[o] = s;
}

extern "C" void kernel_launch(void* const* d_in, const int* in_sizes, int n_in,
                              void* d_out, int out_size, void* d_ws, size_t ws_size,
                              hipStream_t stream) {
    const float* tensor = (const float*)d_in[0];
    const float* Wsh = (const float*)d_in[1];
    const float* Wl = (const float*)d_in[2];
    float* out = (float*)d_out;
    char* ws = (char*)d_ws;

    const size_t bik_bytes = (size_t)32768 * 4096 * sizeof(__half);  // 256 MB

    if (ws_size >= bik_bytes + (2u << 20)) {
        // ---- big path: one GEMM over all (b,t) rows, then the scan ----
        __half* bik = (__half*)ws;
        float* u = (float*)(ws + bik_bytes);                  // 25.6 KB
        float* v = (float*)(ws + bik_bytes + (64 << 10));     // 128 KB

        k_usum<<<6400, 256, 0, stream>>>(Wl, u);
        dim3 g(64, 256);  // 64 i-blocks x 256 row-blocks (32768 rows)
        k_gemm<<<g, 256, 0, stream>>>(tensor, Wsh, bik, 0, 512);
        k_scan<<<512, 256, 0, stream>>>(bik, v);
        k_final<<<200, 256, 0, stream>>>(u, v, out);
    } else {
        // ---- fallback: per-t pipeline, needs ~4.5 MB of ws ----
        __half* bikt = (__half*)ws;                            // 4 MB
        float* u = (float*)(ws + (size_t)(4 << 20));
        float* v0 = (float*)(ws + (size_t)(4 << 20) + (64 << 10));
        float* v1 = v0 + 32768;

        k_usum<<<6400, 256, 0, stream>>>(Wl, u);
        for (int t = 0; t < 64; ++t) {
            dim3 g(64, 4);  // 64 i-blocks x 4 row-blocks (512 rows = b)
            k_gemm<<<g, 256, 0, stream>>>(tensor, Wsh, bikt, t * 512, 32768);
            float* vin = (t & 1) ? v0 : v1;
            float* vout = (t & 1) ? v1 : v0;
            k_update<<<128, 256, 0, stream>>>(bikt, (t == 0) ? v0 : vin, vout, t == 0);
        }
        // t=63 (odd) wrote v1
        k_final<<<200, 256, 0, stream>>>(u, v1, out);
    }
}

// Round 4
// 322.738 us; speedup vs baseline: 5.5472x; 5.5472x over previous
//
#include <hip/hip_runtime.h>
#include <hip/hip_fp16.h>

// tensor  [B=512, T=64, N=512] f32 ; W_shared[R=64, N=512, R=64] f32
// W_last  [C=100, R=64, M=64, R=64] f32 ; out [C=100, B=512] f32
//
// v_b (len 64): v <- v @ M_b(t),  M_b(t)[i,k] = sum_j x[b,t,j] W_shared[i,j,k]
// out[c,b] = sum_i v_b[i] * u[c,i],  u[c,i] = sum_{m,k} W_last[c,i,m,k]
//
// Fast path: fp16 MFMA GEMM  bik[m=b*64+t][i*64+k] = A[m,:] . Bt[i*64+k,:]
//   A  = tensor cast fp16        [32768 x 512]
//   Bt = W transposed, fp16      [4096  x 512]   (Bt[i*64+k][j] = W[i,j,k])

typedef _Float16 f16;
typedef __attribute__((ext_vector_type(8))) _Float16 f16x8;
typedef __attribute__((ext_vector_type(2))) _Float16 f16x2;
typedef __attribute__((ext_vector_type(4))) float f32x4;

#define GLDS16(g, l)                                                      \
    __builtin_amdgcn_global_load_lds(                                     \
        (const __attribute__((address_space(1))) void*)(g),               \
        (__attribute__((address_space(3))) void*)(l), 16, 0, 0)

// ---------------- K1: u[c,i] = sum over 4096 contiguous floats ----------------
__global__ __launch_bounds__(256) void k_usum(const float* __restrict__ Wl,
                                              float* __restrict__ u) {
    int ci = blockIdx.x;  // c*64 + i
    const float4* p = (const float4*)(Wl + (size_t)ci * 4096);
    int tid = threadIdx.x;
    float s = 0.f;
#pragma unroll
    for (int q = 0; q < 4; ++q) {
        float4 v = p[tid + 256 * q];
        s += v.x + v.y + v.z + v.w;
    }
    __shared__ float red[256];
    red[tid] = s;
    __syncthreads();
    if (tid < 128) red[tid] += red[tid + 128];
    __syncthreads();
    if (tid < 64) {
        float x = red[tid] + red[tid + 64];
#pragma unroll
        for (int off = 32; off > 0; off >>= 1) x += __shfl_down(x, off, 64);
        if (tid == 0) u[ci] = x;
    }
}

// ---------------- convert A: fp32 -> fp16, layout preserved -------------------
__global__ __launch_bounds__(256) void k_cvtA(const float* __restrict__ in,
                                              f16* __restrict__ out) {
    int idx = blockIdx.x * 256 + threadIdx.x;  // handles 8 floats
    const float4* p = (const float4*)in + (size_t)idx * 2;
    float4 v0 = p[0], v1 = p[1];
    f16x8 h;
    h[0] = (f16)v0.x; h[1] = (f16)v0.y; h[2] = (f16)v0.z; h[3] = (f16)v0.w;
    h[4] = (f16)v1.x; h[5] = (f16)v1.y; h[6] = (f16)v1.z; h[7] = (f16)v1.w;
    *(f16x8*)(out + (size_t)idx * 8) = h;
}

// ------------- convert W: [i,j,k] fp32 -> Bt[i*64+k][j] fp16 ------------------
__global__ __launch_bounds__(256) void k_cvtW(const float* __restrict__ W,
                                              f16* __restrict__ Bt) {
    int o = blockIdx.x * 256 + threadIdx.x;  // 0..1048575, handles 2 j's
    int col = o >> 8;                        // i*64+k
    int j = (o & 255) << 1;
    int i = col >> 6, k = col & 63;
    const float* src = W + ((size_t)i * 512 + j) * 64 + k;
    f16x2 pk;
    pk[0] = (f16)src[0];
    pk[1] = (f16)src[64];
    *(f16x2*)(Bt + (size_t)col * 512 + j) = pk;
}

// ---------------- fp16 MFMA GEMM: C[m][n] = sum_j A[m][j]*Bt[n][j] ------------
// grid: (x = n-block of 128 [32], y = m-block of 128 [rows/128])
// LDS tiles [128 rows][64 fp16], XOR-swizzled (byte ^= (row&7)<<4) via
// pre-swizzled global source + swizzled ds_read (linear global_load_lds dest).
__global__ __launch_bounds__(256) void k_gemm_mfma(const f16* __restrict__ A,
                                                   const f16* __restrict__ Bt,
                                                   __half* __restrict__ outp,
                                                   int a_off, int a_stride) {
    __shared__ char smem[32768];
    char* AsB = smem;           // 16 KB
    char* BsB = smem + 16384;   // 16 KB

    const int tid = threadIdx.x;
    const int lane = tid & 63;
    const int wid = tid >> 6;
    const int n0 = blockIdx.x * 128;
    const int m0 = blockIdx.y * 128;
    const int wr = wid >> 1, wc = wid & 1;

    f32x4 acc[4][4];
#pragma unroll
    for (int i = 0; i < 4; ++i)
#pragma unroll
        for (int j = 0; j < 4; ++j) acc[i][j] = (f32x4)0.f;

    for (int kt = 0; kt < 8; ++kt) {
        const int k0 = kt * 64;
#pragma unroll
        for (int q = 0; q < 4; ++q) {
            int off = q * 4096 + tid * 16;            // linear LDS byte offset
            int r = off >> 7;                         // tile row
            int ls = (tid & 7) ^ (r & 7);             // pre-swizzled 16B slot
            const f16* ga = A + (size_t)a_off + (size_t)(m0 + r) * a_stride + k0 + ls * 8;
            GLDS16(ga, AsB + q * 4096 + (wid << 10));
            const f16* gb = Bt + (size_t)(n0 + r) * 512 + k0 + ls * 8;
            GLDS16(gb, BsB + q * 4096 + (wid << 10));
        }
        __syncthreads();
#pragma unroll
        for (int kq = 0; kq < 2; ++kq) {
            f16x8 av[4], bv[4];
            const int kb = kq * 64 + ((lane >> 4) << 4);  // byte offset of k in row
#pragma unroll
            for (int f = 0; f < 4; ++f) {
                int ra = wr * 64 + f * 16 + (lane & 15);
                int offa = ((ra << 7) + kb) ^ ((ra & 7) << 4);
                av[f] = *(const f16x8*)(AsB + offa);
                int rb = wc * 64 + f * 16 + (lane & 15);
                int offb = ((rb << 7) + kb) ^ ((rb & 7) << 4);
                bv[f] = *(const f16x8*)(BsB + offb);
            }
#pragma unroll
            for (int mi = 0; mi < 4; ++mi)
#pragma unroll
                for (int ni = 0; ni < 4; ++ni)
                    acc[mi][ni] = __builtin_amdgcn_mfma_f32_16x16x32_f16(
                        av[mi], bv[ni], acc[mi][ni], 0, 0, 0);
        }
        __syncthreads();
    }

    // epilogue: stage C tile (128x128 fp16 = 32 KB) in LDS, store coalesced
    __half* Cs = (__half*)smem;
#pragma unroll
    for (int mi = 0; mi < 4; ++mi)
#pragma unroll
        for (int ni = 0; ni < 4; ++ni)
#pragma unroll
            for (int j = 0; j < 4; ++j) {
                int rm = wr * 64 + mi * 16 + ((lane >> 4) << 2) + j;
                int cn = wc * 64 + ni * 16 + (lane & 15);
                Cs[rm * 128 + cn] = __float2half(acc[mi][ni][j]);
            }
    __syncthreads();
    // 128 rows x 16 float4-segments (128 fp16/row) = 2048 stores = 8 * 256
#pragma unroll
    for (int q = 0; q < 8; ++q) {
        int idx = q * 256 + tid;
        int r = idx >> 4, seg = idx & 15;
        *(float4*)(outp + (size_t)(m0 + r) * 4096 + n0 + seg * 8) =
            *(const float4*)(Cs + r * 128 + seg * 8);
    }
}

// --------- legacy fp32 GEMM (fallback when ws too small for fp16 path) --------
#define BM 128
#define BN 64
#define BK 32
__global__ __launch_bounds__(256) void k_gemm(const float* __restrict__ A,
                                              const float* __restrict__ W,
                                              __half* __restrict__ out,
                                              int a_off, int a_stride) {
    __shared__ float As[BK * BM];
    __shared__ float Bs[BK * BN];
    int i0 = blockIdx.x;
    int m0 = blockIdx.y * BM;
    int tid = threadIdx.x;
    int tx = tid & 15, ty = tid >> 4;
    float acc[8][4];
#pragma unroll
    for (int q = 0; q < 8; ++q)
#pragma unroll
        for (int c = 0; c < 4; ++c) acc[q][c] = 0.f;
    const float* wbase = W + (size_t)i0 * 32768;
    for (int j0 = 0; j0 < 512; j0 += BK) {
        {
            int c4 = tid & 7;
            int r = tid >> 3;
#pragma unroll
            for (int p = 0; p < 4; ++p) {
                int row = r + 32 * p;
                float4 v = *(const float4*)(A + (size_t)a_off +
                                            (size_t)(m0 + row) * a_stride + j0 + 4 * c4);
                As[(4 * c4 + 0) * BM + row] = v.x;
                As[(4 * c4 + 1) * BM + row] = v.y;
                As[(4 * c4 + 2) * BM + row] = v.z;
                As[(4 * c4 + 3) * BM + row] = v.w;
            }
            const float4* src = (const float4*)(wbase + (size_t)j0 * 64);
            float4* dst = (float4*)Bs;
            dst[tid] = src[tid];
            dst[tid + 256] = src[tid + 256];
        }
        __syncthreads();
#pragma unroll
        for (int kk = 0; kk < BK; ++kk) {
            float bv[4], av[8];
#pragma unroll
            for (int c = 0; c < 4; ++c) bv[c] = Bs[kk * BN + 4 * tx + c];
#pragma unroll
            for (int q = 0; q < 8; ++q) av[q] = As[kk * BM + 8 * ty + q];
#pragma unroll
            for (int q = 0; q < 8; ++q)
#pragma unroll
                for (int c = 0; c < 4; ++c) acc[q][c] += av[q] * bv[c];
        }
        __syncthreads();
    }
#pragma unroll
    for (int q = 0; q < 8; ++q) {
        int m = m0 + 8 * ty + q;
        __half* o = out + (size_t)m * 4096 + i0 * 64 + 4 * tx;
#pragma unroll
        for (int c = 0; c < 4; ++c) o[c] = __float2half(acc[q][c]);
    }
}

// ---------------- scan: v_b <- v_b @ M_b(t), t = 0..63 ------------------------
__global__ __launch_bounds__(256) void k_scan(const __half* __restrict__ bik,
                                              float* __restrict__ v_all) {
    int b = blockIdx.x;
    int tid = threadIdx.x;
    int k = tid & 63, grp = tid >> 6;
    __shared__ float vsh[64];
    __shared__ float part[256];
    if (tid < 64) vsh[tid] = 1.0f;
    const __half* base = bik + (size_t)b * 64 * 4096 + grp * 16 * 64 + k;
    __half bufA[16], bufB[16];
#pragma unroll
    for (int q = 0; q < 16; ++q) bufA[q] = base[q * 64];  // t = 0
    __syncthreads();
    for (int t = 0; t < 64; t += 2) {
        {   // even step: compute with bufA, prefetch t+1 into bufB
            const __half* pn = base + (size_t)(t + 1) * 4096;
#pragma unroll
            for (int q = 0; q < 16; ++q) bufB[q] = pn[q * 64];
            float s = 0.f;
#pragma unroll
            for (int q = 0; q < 16; ++q) s += vsh[grp * 16 + q] * __half2float(bufA[q]);
            part[tid] = s;
            __syncthreads();
            if (tid < 64) vsh[k] = part[k] + part[64 + k] + part[128 + k] + part[192 + k];
            __syncthreads();
        }
        {   // odd step: compute with bufB, prefetch t+2 into bufA (clamped)
            int t2 = (t + 2 < 64) ? (t + 2) : 63;
            const __half* pn = base + (size_t)t2 * 4096;
#pragma unroll
            for (int q = 0; q < 16; ++q) bufA[q] = pn[q * 64];
            float s = 0.f;
#pragma unroll
            for (int q = 0; q < 16; ++q) s += vsh[grp * 16 + q] * __half2float(bufB[q]);
            part[tid] = s;
            __syncthreads();
            if (tid < 64) vsh[k] = part[k] + part[64 + k] + part[128 + k] + part[192 + k];
            __syncthreads();
        }
    }
    if (tid < 64) v_all[(size_t)b * 64 + tid] = vsh[tid];
}

// ---------------- fallback per-t update --------------------------------------
__global__ __launch_bounds__(256) void k_update(const __half* __restrict__ Mt,
                                                const float* __restrict__ vin,
                                                float* __restrict__ vout, int first) {
    int o = blockIdx.x * 256 + threadIdx.x;
    int b = o >> 6, k = o & 63;
    const __half* m = Mt + (size_t)b * 4096;
    float s = 0.f;
    if (first) {
#pragma unroll 8
        for (int i = 0; i < 64; ++i) s += __half2float(m[i * 64 + k]);
    } else {
        const float* v = vin + (size_t)b * 64;
#pragma unroll 8
        for (int i = 0; i < 64; ++i) s += v[i] * __half2float(m[i * 64 + k]);
    }
    vout[o] = s;
}

// ---------------- out[c,b] = sum_i u[c,i] * v[b,i] ----------------------------
__global__ __launch_bounds__(256) void k_final(const float* __restrict__ u,
                                               const float* __restrict__ v,
                                               float* __restrict__ out) {
    int o = blockIdx.x * 256 + threadIdx.x;  // c*512 + b
    int c = o >> 9, b = o & 511;
    const float* uc = u + c * 64;
    const float* vb = v + (size_t)b * 64;
    float s = 0.f;
#pragma unroll 8
    for (int i = 0; i < 64; ++i) s += uc[i] * vb[i];
    out[o] = s;
}

extern "C" void kernel_launch(void* const* d_in, const int* in_sizes, int n_in,
                              void* d_out, int out_size, void* d_ws, size_t ws_size,
                              hipStream_t stream) {
    const float* tensor = (const float*)d_in[0];
    const float* Wsh = (const float*)d_in[1];
    const float* Wl = (const float*)d_in[2];
    float* out = (float*)d_out;
    char* ws = (char*)d_ws;

    const size_t bik_bytes = (size_t)32768 * 4096 * sizeof(__half);  // 256 MB
    const size_t fast_bytes = bik_bytes + (512u << 10) + ((size_t)16777216 * 2) + ((size_t)4096 * 512 * 2);

    if (ws_size >= fast_bytes) {
        // ---- fp16 MFMA path ----
        __half* bik = (__half*)ws;
        float* u = (float*)(ws + bik_bytes);
        float* v = (float*)(ws + bik_bytes + (256u << 10));
        f16* Af16 = (f16*)(ws + bik_bytes + (512u << 10));
        f16* Btw = Af16 + (size_t)16777216;

        k_cvtA<<<8192, 256, 0, stream>>>(tensor, Af16);
        k_cvtW<<<4096, 256, 0, stream>>>(Wsh, Btw);
        k_usum<<<6400, 256, 0, stream>>>(Wl, u);
        dim3 g(32, 256);  // n-blocks fastest: B panel L2-resident, A panels shared
        k_gemm_mfma<<<g, 256, 0, stream>>>(Af16, Btw, bik, 0, 512);
        k_scan<<<512, 256, 0, stream>>>(bik, v);
        k_final<<<200, 256, 0, stream>>>(u, v, out);
    } else if (ws_size >= bik_bytes + (2u << 20)) {
        // ---- fp32 big path ----
        __half* bik = (__half*)ws;
        float* u = (float*)(ws + bik_bytes);
        float* v = (float*)(ws + bik_bytes + (64 << 10));

        k_usum<<<6400, 256, 0, stream>>>(Wl, u);
        dim3 g(64, 256);
        k_gemm<<<g, 256, 0, stream>>>(tensor, Wsh, bik, 0, 512);
        k_scan<<<512, 256, 0, stream>>>(bik, v);
        k_final<<<200, 256, 0, stream>>>(u, v, out);
    } else {
        // ---- per-t fallback ----
        __half* bikt = (__half*)ws;
        float* u = (float*)(ws + (size_t)(4 << 20));
        float* v0 = (float*)(ws + (size_t)(4 << 20) + (64 << 10));
        float* v1 = v0 + 32768;

        k_usum<<<6400, 256, 0, stream>>>(Wl, u);
        for (int t = 0; t < 64; ++t) {
            dim3 g(64, 4);
            k_gemm<<<g, 256, 0, stream>>>(tensor, Wsh, bikt, t * 512, 32768);
            float* vin = (t & 1) ? v0 : v1;
            float* vout = (t & 1) ? v1 : v0;
            k_update<<<128, 256, 0, stream>>>(bikt, (t == 0) ? v0 : vin, vout, t == 0);
        }
        k_final<<<200, 256, 0, stream>>>(u, v1, out);
    }
}

// Round 5
// 288.192 us; speedup vs baseline: 6.2121x; 1.1199x over previous
//
#include <hip/hip_runtime.h>
#include <hip/hip_fp16.h>

// tensor  [B=512, T=64, N=512] f32 ; W_shared[R=64, N=512, R=64] f32
// W_last  [C=100, R=64, M=64, R=64] f32 ; out [C=100, B=512] f32
//
// v_b (len 64): v <- v @ M_b(t),  M_b(t)[i,k] = sum_j x[b,t,j] W_shared[i,j,k]
// out[c,b] = sum_i v_b[i] * u[c,i],  u[c,i] = sum_{m,k} W_last[c,i,m,k]
//
// Fast path: fp16 MFMA GEMM  bik[m=b*64+t][i*64+k] = A[m,:] . Bt[i*64+k,:]
//   A  = tensor cast fp16  [32768 x 512] ; Bt = W transposed fp16 [4096 x 512]
// GEMM kernel: 256x256 tile, BK=64, 8 waves (2M x 4N), 8-phase pipeline with
// counted vmcnt (T3+T4), XOR-swizzled LDS (T2), setprio around MFMA (T5).

typedef _Float16 f16;
typedef __attribute__((ext_vector_type(8))) _Float16 f16x8;
typedef __attribute__((ext_vector_type(2))) _Float16 f16x2;
typedef __attribute__((ext_vector_type(4))) float f32x4;

#define GLDS16(g, l)                                                      \
    __builtin_amdgcn_global_load_lds(                                     \
        (const __attribute__((address_space(1))) void*)(g),               \
        (__attribute__((address_space(3))) void*)(l), 16, 0, 0)

#define BARRIER() asm volatile("s_barrier" ::: "memory")
#define VMCNT(n) asm volatile("s_waitcnt vmcnt(" #n ")" ::: "memory")

// ---------------- K1: u[c,i] = sum over 4096 contiguous floats ----------------
__global__ __launch_bounds__(256) void k_usum(const float* __restrict__ Wl,
                                              float* __restrict__ u) {
    int ci = blockIdx.x;  // c*64 + i
    const float4* p = (const float4*)(Wl + (size_t)ci * 4096);
    int tid = threadIdx.x;
    float s = 0.f;
#pragma unroll
    for (int q = 0; q < 4; ++q) {
        float4 v = p[tid + 256 * q];
        s += v.x + v.y + v.z + v.w;
    }
    __shared__ float red[256];
    red[tid] = s;
    __syncthreads();
    if (tid < 128) red[tid] += red[tid + 128];
    __syncthreads();
    if (tid < 64) {
        float x = red[tid] + red[tid + 64];
#pragma unroll
        for (int off = 32; off > 0; off >>= 1) x += __shfl_down(x, off, 64);
        if (tid == 0) u[ci] = x;
    }
}

// ---------------- convert A: fp32 -> fp16, layout preserved -------------------
__global__ __launch_bounds__(256) void k_cvtA(const float* __restrict__ in,
                                              f16* __restrict__ out) {
    int idx = blockIdx.x * 256 + threadIdx.x;  // handles 8 floats
    const float4* p = (const float4*)in + (size_t)idx * 2;
    float4 v0 = p[0], v1 = p[1];
    f16x8 h;
    h[0] = (f16)v0.x; h[1] = (f16)v0.y; h[2] = (f16)v0.z; h[3] = (f16)v0.w;
    h[4] = (f16)v1.x; h[5] = (f16)v1.y; h[6] = (f16)v1.z; h[7] = (f16)v1.w;
    *(f16x8*)(out + (size_t)idx * 8) = h;
}

// ------------- convert W: [i,j,k] fp32 -> Bt[i*64+k][j] fp16 ------------------
__global__ __launch_bounds__(256) void k_cvtW(const float* __restrict__ W,
                                              f16* __restrict__ Bt) {
    int o = blockIdx.x * 256 + threadIdx.x;  // 0..1048575, handles 2 j's
    int col = o >> 8;                        // i*64+k
    int j = (o & 255) << 1;
    int i = col >> 6, k = col & 63;
    const float* src = W + ((size_t)i * 512 + j) * 64 + k;
    f16x2 pk;
    pk[0] = (f16)src[0];
    pk[1] = (f16)src[64];
    *(f16x2*)(Bt + (size_t)col * 512 + j) = pk;
}

// =============== 256x256 8-phase MFMA GEMM ====================================
// LDS (dynamic 128 KB): buf q in {0,1} at q*65536; slots within buf:
//   A0 +0, A1 +16384, B0 +32768, B1 +49152   (each 128 rows x 64 f16 = 16 KB)
// Swizzle invariant: LDS[(r<<7) + s*16] holds global 16B-slot (s ^ (r&7)).
// Stage: 2 global_load_lds per thread per half-tile (linear dest, pre-swizzled
// global source). Read: ds_read_b128 at ((r<<7)+kb) ^ ((r&7)<<4).
//
// Per K-tile (BK=64), 4 phases = quadrants (qa,qb) = (0,0),(0,1),(1,0),(1,1).
// A-frags read once per qa (ph0/ph2, 8 reads), B-frags once per qb (ph1: b1;
// ph0: b0; reg-cached for ph2/ph3). One half-tile staged per phase:
//   ph0: A1@kt+1 (other buf)   ph1: A0@kt+2 (own buf, dead after ph0)
//   ph2: B0@kt+2 (dead ph0)    ph3: B1@kt+2 (dead ph1)
// Waits (protect next phase's ds_reads; queue verified, in-order retirement):
//   steady kt<=5: ph0 vmcnt(10), ph1 vmcnt(10), ph2 none, ph3 vmcnt(10)
//   kt=6 (stages kt+2 skipped): 10, 8, none, 4 ;  kt=7: 2, 0, none, none

#define STAGE_A(qq, ha, ktv) do {                                             \
    _Pragma("unroll") for (int u_ = 0; u_ < 2; ++u_) {                        \
        int idx_ = (wid * 2 + u_) * 64 + lane;                                \
        int r_ = idx_ >> 3;                                                   \
        int ls_ = (idx_ & 7) ^ (r_ & 7);                                      \
        const f16* g_ = A + (size_t)(m0 + (ha) * 128 + r_) * 512              \
                          + (ktv) * 64 + ls_ * 8;                             \
        char* l_ = smem + (qq) * 65536 + (ha) * 16384 + (wid * 2 + u_) * 1024;\
        GLDS16(g_, l_);                                                       \
    } } while (0)

#define STAGE_B(qq, hb, ktv) do {                                             \
    _Pragma("unroll") for (int u_ = 0; u_ < 2; ++u_) {                        \
        int idx_ = (wid * 2 + u_) * 64 + lane;                                \
        int r_ = idx_ >> 3;                                                   \
        int ls_ = (idx_ & 7) ^ (r_ & 7);                                      \
        const f16* g_ = Bt + (size_t)(n0 + (hb) * 128 + r_) * 512             \
                           + (ktv) * 64 + ls_ * 8;                            \
        char* l_ = smem + (qq) * 65536 + 32768 + (hb) * 16384                 \
                        + (wid * 2 + u_) * 1024;                              \
        GLDS16(g_, l_);                                                       \
    } } while (0)

#define RD_A(ha, ktv) do {                                                    \
    _Pragma("unroll") for (int mf_ = 0; mf_ < 4; ++mf_)                       \
    _Pragma("unroll") for (int kq_ = 0; kq_ < 2; ++kq_) {                     \
        int ra_ = wr * 64 + mf_ * 16 + (lane & 15);                           \
        int off_ = ((ra_ << 7) + kq_ * 64 + ((lane >> 4) << 4))               \
                   ^ ((ra_ & 7) << 4);                                        \
        a[mf_][kq_] = *(const f16x8*)(smem + ((ktv) & 1) * 65536              \
                                      + (ha) * 16384 + off_);                 \
    } } while (0)

#define RD_B(hb, ktv, breg) do {                                              \
    _Pragma("unroll") for (int nf_ = 0; nf_ < 2; ++nf_)                       \
    _Pragma("unroll") for (int kq_ = 0; kq_ < 2; ++kq_) {                     \
        int rb_ = wc * 32 + nf_ * 16 + (lane & 15);                           \
        int off_ = ((rb_ << 7) + kq_ * 64 + ((lane >> 4) << 4))               \
                   ^ ((rb_ & 7) << 4);                                        \
        breg[nf_][kq_] = *(const f16x8*)(smem + ((ktv) & 1) * 65536           \
                                         + 32768 + (hb) * 16384 + off_);      \
    } } while (0)

#define MFMA_Q(qa_, qb_, breg) do {                                           \
    __builtin_amdgcn_s_setprio(1);                                            \
    _Pragma("unroll") for (int mf_ = 0; mf_ < 4; ++mf_)                       \
    _Pragma("unroll") for (int nf_ = 0; nf_ < 2; ++nf_)                       \
    _Pragma("unroll") for (int kq_ = 0; kq_ < 2; ++kq_)                       \
        acc[qa_][qb_][mf_][nf_] = __builtin_amdgcn_mfma_f32_16x16x32_f16(     \
            a[mf_][kq_], breg[nf_][kq_], acc[qa_][qb_][mf_][nf_], 0, 0, 0);   \
    __builtin_amdgcn_s_setprio(0);                                            \
    } while (0)

__global__ __launch_bounds__(512) void k_gemm_256(const f16* __restrict__ A,
                                                  const f16* __restrict__ Bt,
                                                  __half* __restrict__ outp) {
    extern __shared__ char smem[];
    const int tid = threadIdx.x;
    const int lane = tid & 63;
    const int wid = tid >> 6;
    // XCD-aware swizzle (nwg=2048, 2048%8==0 -> simple form is bijective)
    int lin = blockIdx.x;
    int swz = (lin & 7) * 256 + (lin >> 3);
    const int n0 = (swz & 15) * 256;   // 16 n-blocks
    const int m0 = (swz >> 4) * 256;   // 128 m-blocks
    const int wr = wid >> 2, wc = wid & 3;  // 2M x 4N waves

    f32x4 acc[2][2][4][2];
#pragma unroll
    for (int x = 0; x < 2; ++x)
#pragma unroll
        for (int y = 0; y < 2; ++y)
#pragma unroll
            for (int z = 0; z < 4; ++z)
#pragma unroll
                for (int w = 0; w < 2; ++w) acc[x][y][z][w] = (f32x4)0.f;

    f16x8 a[4][2], b0[2][2], b1[2][2];

    // prologue: issue order A0@0, B0@0, B1@0, A1@0, A0@1, B0@1, B1@1
    STAGE_A(0, 0, 0);
    STAGE_B(0, 0, 0);
    STAGE_B(0, 1, 0);
    STAGE_A(0, 1, 0);
    STAGE_A(1, 0, 1);
    STAGE_B(1, 0, 1);
    STAGE_B(1, 1, 1);
    VMCNT(10);   // A0@0, B0@0 complete
    BARRIER();

    for (int kt = 0; kt < 6; ++kt) {
        // ---- ph0: quadrant (0,0) ----
        RD_A(0, kt);
        RD_B(0, kt, b0);
        STAGE_A((kt + 1) & 1, 1, kt + 1);   // A1@kt+1
        VMCNT(10);                          // protect ph1 (B1@kt)
        BARRIER();
        MFMA_Q(0, 0, b0);
        BARRIER();
        // ---- ph1: quadrant (0,1) ----
        RD_B(1, kt, b1);
        STAGE_A(kt & 1, 0, kt + 2);         // A0@kt+2
        VMCNT(10);                          // protect ph2 (A1@kt)
        BARRIER();
        MFMA_Q(0, 1, b1);
        BARRIER();
        // ---- ph2: quadrant (1,0) ----
        RD_A(1, kt);
        STAGE_B(kt & 1, 0, kt + 2);         // B0@kt+2
        BARRIER();                          // ph3 reads nothing: no wait
        MFMA_Q(1, 0, b0);
        BARRIER();
        // ---- ph3: quadrant (1,1) ----
        STAGE_B(kt & 1, 1, kt + 2);         // B1@kt+2
        VMCNT(10);                          // protect next kt ph0 (A0,B0)
        BARRIER();
        MFMA_Q(1, 1, b1);
        BARRIER();
    }
    {   // ---- kt = 6 (stages of kt+2 skipped) ----
        RD_A(0, 6);
        RD_B(0, 6, b0);
        STAGE_A(1, 1, 7);                   // A1@7
        VMCNT(10);
        BARRIER();
        MFMA_Q(0, 0, b0);
        BARRIER();
        RD_B(1, 6, b1);
        VMCNT(8);
        BARRIER();
        MFMA_Q(0, 1, b1);
        BARRIER();
        RD_A(1, 6);
        BARRIER();
        MFMA_Q(1, 0, b0);
        BARRIER();
        VMCNT(4);
        BARRIER();
        MFMA_Q(1, 1, b1);
        BARRIER();
    }
    {   // ---- kt = 7 (no stages) ----
        RD_A(0, 7);
        RD_B(0, 7, b0);
        VMCNT(2);
        BARRIER();
        MFMA_Q(0, 0, b0);
        BARRIER();
        RD_B(1, 7, b1);
        VMCNT(0);
        BARRIER();
        MFMA_Q(0, 1, b1);
        BARRIER();
        RD_A(1, 7);
        BARRIER();
        MFMA_Q(1, 0, b0);
        BARRIER();
        BARRIER();
        MFMA_Q(1, 1, b1);
        BARRIER();
    }

    // epilogue: stage 256x256 fp16 C tile in LDS (exactly 128 KB), coalesced out
    __half* Cs = (__half*)smem;
#pragma unroll
    for (int qa = 0; qa < 2; ++qa)
#pragma unroll
        for (int qb = 0; qb < 2; ++qb)
#pragma unroll
            for (int mf = 0; mf < 4; ++mf)
#pragma unroll
                for (int nf = 0; nf < 2; ++nf)
#pragma unroll
                    for (int j = 0; j < 4; ++j) {
                        int row = qa * 128 + wr * 64 + mf * 16 + ((lane >> 4) << 2) + j;
                        int col = qb * 128 + wc * 32 + nf * 16 + (lane & 15);
                        Cs[row * 256 + col] = __float2half(acc[qa][qb][mf][nf][j]);
                    }
    BARRIER();
#pragma unroll
    for (int it = 0; it < 16; ++it) {
        int idx = it * 512 + tid;
        int r = idx >> 5, seg = idx & 31;
        *(float4*)(outp + (size_t)(m0 + r) * 4096 + n0 + seg * 8) =
            *(const float4*)(Cs + r * 256 + seg * 8);
    }
}

// --------- legacy fp32 GEMM (fallback when ws too small for fp16 path) --------
#define BM 128
#define BN 64
#define BK 32
__global__ __launch_bounds__(256) void k_gemm(const float* __restrict__ A,
                                              const float* __restrict__ W,
                                              __half* __restrict__ out,
                                              int a_off, int a_stride) {
    __shared__ float As[BK * BM];
    __shared__ float Bs[BK * BN];
    int i0 = blockIdx.x;
    int m0 = blockIdx.y * BM;
    int tid = threadIdx.x;
    int tx = tid & 15, ty = tid >> 4;
    float acc[8][4];
#pragma unroll
    for (int q = 0; q < 8; ++q)
#pragma unroll
        for (int c = 0; c < 4; ++c) acc[q][c] = 0.f;
    const float* wbase = W + (size_t)i0 * 32768;
    for (int j0 = 0; j0 < 512; j0 += BK) {
        {
            int c4 = tid & 7;
            int r = tid >> 3;
#pragma unroll
            for (int p = 0; p < 4; ++p) {
                int row = r + 32 * p;
                float4 v = *(const float4*)(A + (size_t)a_off +
                                            (size_t)(m0 + row) * a_stride + j0 + 4 * c4);
                As[(4 * c4 + 0) * BM + row] = v.x;
                As[(4 * c4 + 1) * BM + row] = v.y;
                As[(4 * c4 + 2) * BM + row] = v.z;
                As[(4 * c4 + 3) * BM + row] = v.w;
            }
            const float4* src = (const float4*)(wbase + (size_t)j0 * 64);
            float4* dst = (float4*)Bs;
            dst[tid] = src[tid];
            dst[tid + 256] = src[tid + 256];
        }
        __syncthreads();
#pragma unroll
        for (int kk = 0; kk < BK; ++kk) {
            float bv[4], av[8];
#pragma unroll
            for (int c = 0; c < 4; ++c) bv[c] = Bs[kk * BN + 4 * tx + c];
#pragma unroll
            for (int q = 0; q < 8; ++q) av[q] = As[kk * BM + 8 * ty + q];
#pragma unroll
            for (int q = 0; q < 8; ++q)
#pragma unroll
                for (int c = 0; c < 4; ++c) acc[q][c] += av[q] * bv[c];
        }
        __syncthreads();
    }
#pragma unroll
    for (int q = 0; q < 8; ++q) {
        int m = m0 + 8 * ty + q;
        __half* o = out + (size_t)m * 4096 + i0 * 64 + 4 * tx;
#pragma unroll
        for (int c = 0; c < 4; ++c) o[c] = __float2half(acc[q][c]);
    }
}

// ---------------- scan: v_b <- v_b @ M_b(t), t = 0..63 ------------------------
__global__ __launch_bounds__(256) void k_scan(const __half* __restrict__ bik,
                                              float* __restrict__ v_all) {
    int b = blockIdx.x;
    int tid = threadIdx.x;
    int k = tid & 63, grp = tid >> 6;
    __shared__ float vsh[64];
    __shared__ float part[256];
    if (tid < 64) vsh[tid] = 1.0f;
    const __half* base = bik + (size_t)b * 64 * 4096 + grp * 16 * 64 + k;
    __half bufA[16], bufB[16];
#pragma unroll
    for (int q = 0; q < 16; ++q) bufA[q] = base[q * 64];  // t = 0
    __syncthreads();
    for (int t = 0; t < 64; t += 2) {
        {   // even step: compute with bufA, prefetch t+1 into bufB
            const __half* pn = base + (size_t)(t + 1) * 4096;
#pragma unroll
            for (int q = 0; q < 16; ++q) bufB[q] = pn[q * 64];
            float s = 0.f;
#pragma unroll
            for (int q = 0; q < 16; ++q) s += vsh[grp * 16 + q] * __half2float(bufA[q]);
            part[tid] = s;
            __syncthreads();
            if (tid < 64) vsh[k] = part[k] + part[64 + k] + part[128 + k] + part[192 + k];
            __syncthreads();
        }
        {   // odd step: compute with bufB, prefetch t+2 into bufA (clamped)
            int t2 = (t + 2 < 64) ? (t + 2) : 63;
            const __half* pn = base + (size_t)t2 * 4096;
#pragma unroll
            for (int q = 0; q < 16; ++q) bufA[q] = pn[q * 64];
            float s = 0.f;
#pragma unroll
            for (int q = 0; q < 16; ++q) s += vsh[grp * 16 + q] * __half2float(bufB[q]);
            part[tid] = s;
            __syncthreads();
            if (tid < 64) vsh[k] = part[k] + part[64 + k] + part[128 + k] + part[192 + k];
            __syncthreads();
        }
    }
    if (tid < 64) v_all[(size_t)b * 64 + tid] = vsh[tid];
}

// ---------------- fallback per-t update --------------------------------------
__global__ __launch_bounds__(256) void k_update(const __half* __restrict__ Mt,
                                                const float* __restrict__ vin,
                                                float* __restrict__ vout, int first) {
    int o = blockIdx.x * 256 + threadIdx.x;
    int b = o >> 6, k = o & 63;
    const __half* m = Mt + (size_t)b * 4096;
    float s = 0.f;
    if (first) {
#pragma unroll 8
        for (int i = 0; i < 64; ++i) s += __half2float(m[i * 64 + k]);
    } else {
        const float* v = vin + (size_t)b * 64;
#pragma unroll 8
        for (int i = 0; i < 64; ++i) s += v[i] * __half2float(m[i * 64 + k]);
    }
    vout[o] = s;
}

// ---------------- out[c,b] = sum_i u[c,i] * v[b,i] ----------------------------
__global__ __launch_bounds__(256) void k_final(const float* __restrict__ u,
                                               const float* __restrict__ v,
                                               float* __restrict__ out) {
    int o = blockIdx.x * 256 + threadIdx.x;  // c*512 + b
    int c = o >> 9, b = o & 511;
    const float* uc = u + c * 64;
    const float* vb = v + (size_t)b * 64;
    float s = 0.f;
#pragma unroll 8
    for (int i = 0; i < 64; ++i) s += uc[i] * vb[i];
    out[o] = s;
}

extern "C" void kernel_launch(void* const* d_in, const int* in_sizes, int n_in,
                              void* d_out, int out_size, void* d_ws, size_t ws_size,
                              hipStream_t stream) {
    const float* tensor = (const float*)d_in[0];
    const float* Wsh = (const float*)d_in[1];
    const float* Wl = (const float*)d_in[2];
    float* out = (float*)d_out;
    char* ws = (char*)d_ws;

    const size_t bik_bytes = (size_t)32768 * 4096 * sizeof(__half);  // 256 MB
    const size_t fast_bytes = bik_bytes + (512u << 10) + ((size_t)16777216 * 2) + ((size_t)4096 * 512 * 2);

    if (ws_size >= fast_bytes) {
        // ---- fp16 MFMA 8-phase path ----
        __half* bik = (__half*)ws;
        float* u = (float*)(ws + bik_bytes);
        float* v = (float*)(ws + bik_bytes + (256u << 10));
        f16* Af16 = (f16*)(ws + bik_bytes + (512u << 10));
        f16* Btw = Af16 + (size_t)16777216;

        k_cvtA<<<8192, 256, 0, stream>>>(tensor, Af16);
        k_cvtW<<<4096, 256, 0, stream>>>(Wsh, Btw);
        k_usum<<<6400, 256, 0, stream>>>(Wl, u);
        (void)hipFuncSetAttribute((const void*)k_gemm_256,
                                  hipFuncAttributeMaxDynamicSharedMemorySize, 131072);
        k_gemm_256<<<2048, 512, 131072, stream>>>(Af16, Btw, bik);
        k_scan<<<512, 256, 0, stream>>>(bik, v);
        k_final<<<200, 256, 0, stream>>>(u, v, out);
    } else if (ws_size >= bik_bytes + (2u << 20)) {
        // ---- fp32 big path ----
        __half* bik = (__half*)ws;
        float* u = (float*)(ws + bik_bytes);
        float* v = (float*)(ws + bik_bytes + (64 << 10));

        k_usum<<<6400, 256, 0, stream>>>(Wl, u);
        dim3 g(64, 256);
        k_gemm<<<g, 256, 0, stream>>>(tensor, Wsh, bik, 0, 512);
        k_scan<<<512, 256, 0, stream>>>(bik, v);
        k_final<<<200, 256, 0, stream>>>(u, v, out);
    } else {
        // ---- per-t fallback ----
        __half* bikt = (__half*)ws;
        float* u = (float*)(ws + (size_t)(4 << 20));
        float* v0 = (float*)(ws + (size_t)(4 << 20) + (64 << 10));
        float* v1 = v0 + 32768;

        k_usum<<<6400, 256, 0, stream>>>(Wl, u);
        for (int t = 0; t < 64; ++t) {
            dim3 g(64, 4);
            k_gemm<<<g, 256, 0, stream>>>(tensor, Wsh, bikt, t * 512, 32768);
            float* vin = (t & 1) ? v0 : v1;
            float* vout = (t & 1) ? v1 : v0;
            k_update<<<128, 256, 0, stream>>>(bikt, (t == 0) ? v0 : vin, vout, t == 0);
        }
        k_final<<<200, 256, 0, stream>>>(u, v1, out);
    }
}

// Round 6
// 282.820 us; speedup vs baseline: 6.3301x; 1.0190x over previous
//
#include <hip/hip_runtime.h>
#include <hip/hip_fp16.h>

// tensor  [B=512, T=64, N=512] f32 ; W_shared[R=64, N=512, R=64] f32
// W_last  [C=100, R=64, M=64, R=64] f32 ; out [C=100, B=512] f32
//
// v_b (len 64): v <- v @ M_b(t),  M_b(t)[i,k] = sum_j x[b,t,j] W_shared[i,j,k]
// out[c,b] = sum_i v_b[i] * u[c,i],  u[c,i] = sum_{m,k} W_last[c,i,m,k]
//
// Fast path: fp16 MFMA GEMM  bik[m=b*64+t][i*64+k] = A[m,:] . Bt[i*64+k,:]
// 256x256 tile, BK=64, 8 waves (2M x 4N). Round-6: 4 barriers + 1 counted
// vmcnt per K-tile (was 8+3). Stages target slots dead >=2 phases; safety:
// every phase-p ds_read is lgkmcnt-complete before BAR_{p+1} (its MFMA
// consumes it pre-barrier), and each stage issues after BAR_{p+2}.

typedef _Float16 f16;
typedef __attribute__((ext_vector_type(8))) _Float16 f16x8;
typedef __attribute__((ext_vector_type(2))) _Float16 f16x2;
typedef __attribute__((ext_vector_type(4))) float f32x4;

#define GLDS16(g, l)                                                      \
    __builtin_amdgcn_global_load_lds(                                     \
        (const __attribute__((address_space(1))) void*)(g),               \
        (__attribute__((address_space(3))) void*)(l), 16, 0, 0)

#define BARRIER() asm volatile("s_barrier" ::: "memory")
#define VMCNT(n) asm volatile("s_waitcnt vmcnt(" #n ")" ::: "memory")

// ---------------- K1: u[c,i] = sum over 4096 contiguous floats ----------------
__global__ __launch_bounds__(256) void k_usum(const float* __restrict__ Wl,
                                              float* __restrict__ u) {
    int ci = blockIdx.x;  // c*64 + i
    const float4* p = (const float4*)(Wl + (size_t)ci * 4096);
    int tid = threadIdx.x;
    float s = 0.f;
#pragma unroll
    for (int q = 0; q < 4; ++q) {
        float4 v = p[tid + 256 * q];
        s += v.x + v.y + v.z + v.w;
    }
    __shared__ float red[256];
    red[tid] = s;
    __syncthreads();
    if (tid < 128) red[tid] += red[tid + 128];
    __syncthreads();
    if (tid < 64) {
        float x = red[tid] + red[tid + 64];
#pragma unroll
        for (int off = 32; off > 0; off >>= 1) x += __shfl_down(x, off, 64);
        if (tid == 0) u[ci] = x;
    }
}

// ---------------- convert A: fp32 -> fp16, layout preserved -------------------
__global__ __launch_bounds__(256) void k_cvtA(const float* __restrict__ in,
                                              f16* __restrict__ out) {
    int idx = blockIdx.x * 256 + threadIdx.x;  // handles 8 floats
    const float4* p = (const float4*)in + (size_t)idx * 2;
    float4 v0 = p[0], v1 = p[1];
    f16x8 h;
    h[0] = (f16)v0.x; h[1] = (f16)v0.y; h[2] = (f16)v0.z; h[3] = (f16)v0.w;
    h[4] = (f16)v1.x; h[5] = (f16)v1.y; h[6] = (f16)v1.z; h[7] = (f16)v1.w;
    *(f16x8*)(out + (size_t)idx * 8) = h;
}

// ------------- convert W: [i,j,k] fp32 -> Bt[i*64+k][j] fp16 ------------------
__global__ __launch_bounds__(256) void k_cvtW(const float* __restrict__ W,
                                              f16* __restrict__ Bt) {
    int o = blockIdx.x * 256 + threadIdx.x;  // 0..1048575, handles 2 j's
    int col = o >> 8;                        // i*64+k
    int j = (o & 255) << 1;
    int i = col >> 6, k = col & 63;
    const float* src = W + ((size_t)i * 512 + j) * 64 + k;
    f16x2 pk;
    pk[0] = (f16)src[0];
    pk[1] = (f16)src[64];
    *(f16x2*)(Bt + (size_t)col * 512 + j) = pk;
}

// =============== 256x256 MFMA GEMM, 4-barrier/1-vmcnt K-tiles =================
// LDS (dynamic 128 KB): buf q in {0,1} at q*65536; slots within buf:
//   A0 +0, A1 +16384, B0 +32768, B1 +49152   (each 128 rows x 64 f16 = 16 KB)
// Swizzle invariant: LDS[(r<<7) + s*16] holds global 16B-slot (s ^ (r&7)).
//
// Stage schedule (slot dead >=2 phases before stage issue):
//   ph0: A1@kt+1 (slot last read ph2 of kt-1)
//   ph2: A0@kt+2, B0@kt+2 (slots last read ph0 of kt)
//   ph3: B1@kt+2 (slot last read ph1 of kt)
// Issue order: ..., A1@kt+1, A0@kt+2, B0@kt+2, B1@kt+2, A1@kt+2, ...
// Wait: top-of-kt VMCNT(6) completes all four kt half-tiles (outstanding
// after A1@kt = A0/B0/B1@kt+1 = 6 loads). Tail: kt6 VMCNT(6), kt7 VMCNT(0).

#define STAGE_A(qq, ha, ktv) do {                                             \
    _Pragma("unroll") for (int u_ = 0; u_ < 2; ++u_) {                        \
        int idx_ = (wid * 2 + u_) * 64 + lane;                                \
        int r_ = idx_ >> 3;                                                   \
        int ls_ = (idx_ & 7) ^ (r_ & 7);                                      \
        const f16* g_ = A + (size_t)(m0 + (ha) * 128 + r_) * 512              \
                          + (ktv) * 64 + ls_ * 8;                             \
        char* l_ = smem + (qq) * 65536 + (ha) * 16384 + (wid * 2 + u_) * 1024;\
        GLDS16(g_, l_);                                                       \
    } } while (0)

#define STAGE_B(qq, hb, ktv) do {                                             \
    _Pragma("unroll") for (int u_ = 0; u_ < 2; ++u_) {                        \
        int idx_ = (wid * 2 + u_) * 64 + lane;                                \
        int r_ = idx_ >> 3;                                                   \
        int ls_ = (idx_ & 7) ^ (r_ & 7);                                      \
        const f16* g_ = Bt + (size_t)(n0 + (hb) * 128 + r_) * 512             \
                           + (ktv) * 64 + ls_ * 8;                            \
        char* l_ = smem + (qq) * 65536 + 32768 + (hb) * 16384                 \
                        + (wid * 2 + u_) * 1024;                              \
        GLDS16(g_, l_);                                                       \
    } } while (0)

#define RD_A(ha, ktv) do {                                                    \
    _Pragma("unroll") for (int mf_ = 0; mf_ < 4; ++mf_)                       \
    _Pragma("unroll") for (int kq_ = 0; kq_ < 2; ++kq_) {                     \
        int ra_ = wr * 64 + mf_ * 16 + (lane & 15);                           \
        int off_ = ((ra_ << 7) + kq_ * 64 + ((lane >> 4) << 4))               \
                   ^ ((ra_ & 7) << 4);                                        \
        a[mf_][kq_] = *(const f16x8*)(smem + ((ktv) & 1) * 65536              \
                                      + (ha) * 16384 + off_);                 \
    } } while (0)

#define RD_B(hb, ktv, breg) do {                                              \
    _Pragma("unroll") for (int nf_ = 0; nf_ < 2; ++nf_)                       \
    _Pragma("unroll") for (int kq_ = 0; kq_ < 2; ++kq_) {                     \
        int rb_ = wc * 32 + nf_ * 16 + (lane & 15);                           \
        int off_ = ((rb_ << 7) + kq_ * 64 + ((lane >> 4) << 4))               \
                   ^ ((rb_ & 7) << 4);                                        \
        breg[nf_][kq_] = *(const f16x8*)(smem + ((ktv) & 1) * 65536           \
                                         + 32768 + (hb) * 16384 + off_);      \
    } } while (0)

#define MFMA_Q(qa_, qb_, breg) do {                                           \
    __builtin_amdgcn_s_setprio(1);                                            \
    _Pragma("unroll") for (int mf_ = 0; mf_ < 4; ++mf_)                       \
    _Pragma("unroll") for (int nf_ = 0; nf_ < 2; ++nf_)                       \
    _Pragma("unroll") for (int kq_ = 0; kq_ < 2; ++kq_)                       \
        acc[qa_][qb_][mf_][nf_] = __builtin_amdgcn_mfma_f32_16x16x32_f16(     \
            a[mf_][kq_], breg[nf_][kq_], acc[qa_][qb_][mf_][nf_], 0, 0, 0);   \
    __builtin_amdgcn_s_setprio(0);                                            \
    } while (0)

__global__ __launch_bounds__(512) void k_gemm_256(const f16* __restrict__ A,
                                                  const f16* __restrict__ Bt,
                                                  __half* __restrict__ outp) {
    extern __shared__ char smem[];
    const int tid = threadIdx.x;
    const int lane = tid & 63;
    const int wid = tid >> 6;
    // XCD-aware swizzle (nwg=2048, 2048%8==0 -> simple form is bijective)
    int lin = blockIdx.x;
    int swz = (lin & 7) * 256 + (lin >> 3);
    const int n0 = (swz & 15) * 256;   // 16 n-blocks
    const int m0 = (swz >> 4) * 256;   // 128 m-blocks
    const int wr = wid >> 2, wc = wid & 3;  // 2M x 4N waves

    f32x4 acc[2][2][4][2];
#pragma unroll
    for (int x = 0; x < 2; ++x)
#pragma unroll
        for (int y = 0; y < 2; ++y)
#pragma unroll
            for (int z = 0; z < 4; ++z)
#pragma unroll
                for (int w = 0; w < 2; ++w) acc[x][y][z][w] = (f32x4)0.f;

    f16x8 a[4][2], b0[2][2], b1[2][2];

    // prologue: kt0 all four (A0,B0,B1,A1), kt1 three (A0,B0,B1)
    STAGE_A(0, 0, 0);
    STAGE_B(0, 0, 0);
    STAGE_B(0, 1, 0);
    STAGE_A(0, 1, 0);
    STAGE_A(1, 0, 1);
    STAGE_B(1, 0, 1);
    STAGE_B(1, 1, 1);

    for (int kt = 0; kt < 6; ++kt) {
        VMCNT(6);                            // kt's 4 half-tiles complete
        BARRIER();                           // ...and visible to all waves
        // ph0
        RD_A(0, kt);
        RD_B(0, kt, b0);
        STAGE_A((kt + 1) & 1, 1, kt + 1);    // A1@kt+1 (dead since ph2 kt-1)
        MFMA_Q(0, 0, b0);
        BARRIER();
        // ph1
        RD_B(1, kt, b1);
        MFMA_Q(0, 1, b1);
        BARRIER();
        // ph2
        RD_A(1, kt);
        STAGE_A(kt & 1, 0, kt + 2);          // A0@kt+2 (dead since ph0)
        STAGE_B(kt & 1, 0, kt + 2);          // B0@kt+2 (dead since ph0)
        MFMA_Q(1, 0, b0);
        BARRIER();
        // ph3
        STAGE_B(kt & 1, 1, kt + 2);          // B1@kt+2 (dead since ph1)
        MFMA_Q(1, 1, b1);
        BARRIER();
    }
    {   // ---- kt = 6 (no kt+2 stages) ----
        VMCNT(6);
        BARRIER();
        RD_A(0, 6);
        RD_B(0, 6, b0);
        STAGE_A(1, 1, 7);                    // A1@7
        MFMA_Q(0, 0, b0);
        BARRIER();
        RD_B(1, 6, b1);
        MFMA_Q(0, 1, b1);
        BARRIER();
        RD_A(1, 6);
        MFMA_Q(1, 0, b0);
        BARRIER();
        MFMA_Q(1, 1, b1);
        BARRIER();
    }
    {   // ---- kt = 7 (no stages) ----
        VMCNT(0);
        BARRIER();
        RD_A(0, 7);
        RD_B(0, 7, b0);
        MFMA_Q(0, 0, b0);
        BARRIER();
        RD_B(1, 7, b1);
        MFMA_Q(0, 1, b1);
        BARRIER();
        RD_A(1, 7);
        MFMA_Q(1, 0, b0);
        BARRIER();
        MFMA_Q(1, 1, b1);
        BARRIER();
    }

    // epilogue: stage 256x256 fp16 C tile in LDS (exactly 128 KB), coalesced out
    __half* Cs = (__half*)smem;
#pragma unroll
    for (int qa = 0; qa < 2; ++qa)
#pragma unroll
        for (int qb = 0; qb < 2; ++qb)
#pragma unroll
            for (int mf = 0; mf < 4; ++mf)
#pragma unroll
                for (int nf = 0; nf < 2; ++nf)
#pragma unroll
                    for (int j = 0; j < 4; ++j) {
                        int row = qa * 128 + wr * 64 + mf * 16 + ((lane >> 4) << 2) + j;
                        int col = qb * 128 + wc * 32 + nf * 16 + (lane & 15);
                        Cs[row * 256 + col] = __float2half(acc[qa][qb][mf][nf][j]);
                    }
    BARRIER();
#pragma unroll
    for (int it = 0; it < 16; ++it) {
        int idx = it * 512 + tid;
        int r = idx >> 5, seg = idx & 31;
        *(float4*)(outp + (size_t)(m0 + r) * 4096 + n0 + seg * 8) =
            *(const float4*)(Cs + r * 256 + seg * 8);
    }
}

// --------- legacy fp32 GEMM (fallback when ws too small for fp16 path) --------
#define BM 128
#define BN 64
#define BK 32
__global__ __launch_bounds__(256) void k_gemm(const float* __restrict__ A,
                                              const float* __restrict__ W,
                                              __half* __restrict__ out,
                                              int a_off, int a_stride) {
    __shared__ float As[BK * BM];
    __shared__ float Bs[BK * BN];
    int i0 = blockIdx.x;
    int m0 = blockIdx.y * BM;
    int tid = threadIdx.x;
    int tx = tid & 15, ty = tid >> 4;
    float acc[8][4];
#pragma unroll
    for (int q = 0; q < 8; ++q)
#pragma unroll
        for (int c = 0; c < 4; ++c) acc[q][c] = 0.f;
    const float* wbase = W + (size_t)i0 * 32768;
    for (int j0 = 0; j0 < 512; j0 += BK) {
        {
            int c4 = tid & 7;
            int r = tid >> 3;
#pragma unroll
            for (int p = 0; p < 4; ++p) {
                int row = r + 32 * p;
                float4 v = *(const float4*)(A + (size_t)a_off +
                                            (size_t)(m0 + row) * a_stride + j0 + 4 * c4);
                As[(4 * c4 + 0) * BM + row] = v.x;
                As[(4 * c4 + 1) * BM + row] = v.y;
                As[(4 * c4 + 2) * BM + row] = v.z;
                As[(4 * c4 + 3) * BM + row] = v.w;
            }
            const float4* src = (const float4*)(wbase + (size_t)j0 * 64);
            float4* dst = (float4*)Bs;
            dst[tid] = src[tid];
            dst[tid + 256] = src[tid + 256];
        }
        __syncthreads();
#pragma unroll
        for (int kk = 0; kk < BK; ++kk) {
            float bv[4], av[8];
#pragma unroll
            for (int c = 0; c < 4; ++c) bv[c] = Bs[kk * BN + 4 * tx + c];
#pragma unroll
            for (int q = 0; q < 8; ++q) av[q] = As[kk * BM + 8 * ty + q];
#pragma unroll
            for (int q = 0; q < 8; ++q)
#pragma unroll
                for (int c = 0; c < 4; ++c) acc[q][c] += av[q] * bv[c];
        }
        __syncthreads();
    }
#pragma unroll
    for (int q = 0; q < 8; ++q) {
        int m = m0 + 8 * ty + q;
        __half* o = out + (size_t)m * 4096 + i0 * 64 + 4 * tx;
#pragma unroll
        for (int c = 0; c < 4; ++c) o[c] = __float2half(acc[q][c]);
    }
}

// ---------- scan: v_b <- v_b @ M_b(t), t=0..63, + fused out[c,b] --------------
__global__ __launch_bounds__(256) void k_scan(const __half* __restrict__ bik,
                                              const float* __restrict__ u,
                                              float* __restrict__ out) {
    int b = blockIdx.x;
    int tid = threadIdx.x;
    int k = tid & 63, grp = tid >> 6;
    __shared__ float vsh[64];
    __shared__ float part[256];
    if (tid < 64) vsh[tid] = 1.0f;
    const __half* base = bik + (size_t)b * 64 * 4096 + grp * 16 * 64 + k;
    __half bufA[16], bufB[16];
#pragma unroll
    for (int q = 0; q < 16; ++q) bufA[q] = base[q * 64];  // t = 0
    __syncthreads();
    for (int t = 0; t < 64; t += 2) {
        {   // even step: compute with bufA, prefetch t+1 into bufB
            const __half* pn = base + (size_t)(t + 1) * 4096;
#pragma unroll
            for (int q = 0; q < 16; ++q) bufB[q] = pn[q * 64];
            float s = 0.f;
#pragma unroll
            for (int q = 0; q < 16; ++q) s += vsh[grp * 16 + q] * __half2float(bufA[q]);
            part[tid] = s;
            __syncthreads();
            if (tid < 64) vsh[k] = part[k] + part[64 + k] + part[128 + k] + part[192 + k];
            __syncthreads();
        }
        {   // odd step: compute with bufB, prefetch t+2 into bufA (clamped)
            int t2 = (t + 2 < 64) ? (t + 2) : 63;
            const __half* pn = base + (size_t)t2 * 4096;
#pragma unroll
            for (int q = 0; q < 16; ++q) bufA[q] = pn[q * 64];
            float s = 0.f;
#pragma unroll
            for (int q = 0; q < 16; ++q) s += vsh[grp * 16 + q] * __half2float(bufB[q]);
            part[tid] = s;
            __syncthreads();
            if (tid < 64) vsh[k] = part[k] + part[64 + k] + part[128 + k] + part[192 + k];
            __syncthreads();
        }
    }
    // fused epilogue: out[c, b] = sum_i u[c,i] * v[i]
    if (tid < 100) {
        const float* uc = u + tid * 64;
        float s = 0.f;
#pragma unroll 8
        for (int i = 0; i < 64; ++i) s += uc[i] * vsh[i];
        out[tid * 512 + b] = s;
    }
}

// ---------------- fallback per-t update --------------------------------------
__global__ __launch_bounds__(256) void k_update(const __half* __restrict__ Mt,
                                                const float* __restrict__ vin,
                                                float* __restrict__ vout, int first) {
    int o = blockIdx.x * 256 + threadIdx.x;
    int b = o >> 6, k = o & 63;
    const __half* m = Mt + (size_t)b * 4096;
    float s = 0.f;
    if (first) {
#pragma unroll 8
        for (int i = 0; i < 64; ++i) s += __half2float(m[i * 64 + k]);
    } else {
        const float* v = vin + (size_t)b * 64;
#pragma unroll 8
        for (int i = 0; i < 64; ++i) s += v[i] * __half2float(m[i * 64 + k]);
    }
    vout[o] = s;
}

// ---------------- out[c,b] = sum_i u[c,i] * v[b,i] (fallback path) ------------
__global__ __launch_bounds__(256) void k_final(const float* __restrict__ u,
                                               const float* __restrict__ v,
                                               float* __restrict__ out) {
    int o = blockIdx.x * 256 + threadIdx.x;  // c*512 + b
    int c = o >> 9, b = o & 511;
    const float* uc = u + c * 64;
    const float* vb = v + (size_t)b * 64;
    float s = 0.f;
#pragma unroll 8
    for (int i = 0; i < 64; ++i) s += uc[i] * vb[i];
    out[o] = s;
}

extern "C" void kernel_launch(void* const* d_in, const int* in_sizes, int n_in,
                              void* d_out, int out_size, void* d_ws, size_t ws_size,
                              hipStream_t stream) {
    const float* tensor = (const float*)d_in[0];
    const float* Wsh = (const float*)d_in[1];
    const float* Wl = (const float*)d_in[2];
    float* out = (float*)d_out;
    char* ws = (char*)d_ws;

    const size_t bik_bytes = (size_t)32768 * 4096 * sizeof(__half);  // 256 MB
    const size_t fast_bytes = bik_bytes + (512u << 10) + ((size_t)16777216 * 2) + ((size_t)4096 * 512 * 2);

    if (ws_size >= fast_bytes) {
        // ---- fp16 MFMA path ----
        __half* bik = (__half*)ws;
        float* u = (float*)(ws + bik_bytes);
        f16* Af16 = (f16*)(ws + bik_bytes + (512u << 10));
        f16* Btw = Af16 + (size_t)16777216;

        k_cvtA<<<8192, 256, 0, stream>>>(tensor, Af16);
        k_cvtW<<<4096, 256, 0, stream>>>(Wsh, Btw);
        k_usum<<<6400, 256, 0, stream>>>(Wl, u);
        (void)hipFuncSetAttribute((const void*)k_gemm_256,
                                  hipFuncAttributeMaxDynamicSharedMemorySize, 131072);
        k_gemm_256<<<2048, 512, 131072, stream>>>(Af16, Btw, bik);
        k_scan<<<512, 256, 0, stream>>>(bik, u, out);
    } else if (ws_size >= bik_bytes + (2u << 20)) {
        // ---- fp32 big path ----
        __half* bik = (__half*)ws;
        float* u = (float*)(ws + bik_bytes);

        k_usum<<<6400, 256, 0, stream>>>(Wl, u);
        dim3 g(64, 256);
        k_gemm<<<g, 256, 0, stream>>>(tensor, Wsh, bik, 0, 512);
        k_scan<<<512, 256, 0, stream>>>(bik, u, out);
    } else {
        // ---- per-t fallback ----
        __half* bikt = (__half*)ws;
        float* u = (float*)(ws + (size_t)(4 << 20));
        float* v0 = (float*)(ws + (size_t)(4 << 20) + (64 << 10));
        float* v1 = v0 + 32768;

        k_usum<<<6400, 256, 0, stream>>>(Wl, u);
        for (int t = 0; t < 64; ++t) {
            dim3 g(64, 4);
            k_gemm<<<g, 256, 0, stream>>>(tensor, Wsh, bikt, t * 512, 32768);
            float* vin = (t & 1) ? v0 : v1;
            float* vout = (t & 1) ? v1 : v0;
            k_update<<<128, 256, 0, stream>>>(bikt, (t == 0) ? v0 : vin, vout, t == 0);
        }
        k_final<<<200, 256, 0, stream>>>(u, v1, out);
    }
}